// Round 15
// baseline (155.518 us; speedup 1.0000x reference)
//
#include <hip/hip_runtime.h>

#define FDIM 32
#define BSHIFT 8                 // 256 cols per bucket
#define CPB (1 << BSHIFT)
#define CMASK (CPB - 1)
#define PAD 16                   // cursor stride: 16 u32 = 64B (one cacheline)
#define MAXBUK 512
#define BNT 2048                 // binsort tile (edges per WG, 8/thread)
#define LCAP 12288               // csort LDS staging capacity (48 KB)

// ---------- one-launch zero of bcur + pool + cnt ----------
__global__ void k_zero(int* __restrict__ bcur, float* __restrict__ pool, int nb, int np) {
    int i = blockIdx.x * blockDim.x + threadIdx.x;
    if (i < nb) bcur[i] = 0;
    if (i < np) pool[i] = 0.0f;
}

// ---------- LDS-staged binning into fixed-capacity bucket regions ----------
// pack: (col & 255) << 24 | row   (needs N < 2^24)
__global__ void k_binsort(const int* __restrict__ row, const int* __restrict__ col,
                          int* bcur, unsigned int* __restrict__ buf, int E, int cap, int NBUK) {
    __shared__ unsigned int lh[MAXBUK];      // hist -> global cursor
    __shared__ int lbase[MAXBUK];            // local exclusive base (monotone)
    __shared__ int gbase[MAXBUK];            // global segment base
    __shared__ unsigned int swave[4];
    __shared__ unsigned int lpair[BNT];      // staged packed pairs (rank order)
    int t = threadIdx.x;
    int w = t >> 6, lane = t & 63;
    int base = blockIdx.x * BNT;
    int end = min(base + BNT, E);

    lh[t] = 0u; lh[t + 256] = 0u;
    __syncthreads();

    // phase 1: tile histogram; int4-vectorized (col,row) loads cached in registers.
    int cl[8], rw[8];
    #pragma unroll
    for (int k = 0; k < 2; ++k) {
        int e4 = (base >> 2) + k * 256 + t;       // edge block [4*e4, 4*e4+4)
        int eb = 4 * e4;
        if (eb + 3 < end) {
            int4 c4 = *(const int4*)(col + eb);
            int4 r4 = *(const int4*)(row + eb);
            cl[4*k] = c4.x; cl[4*k+1] = c4.y; cl[4*k+2] = c4.z; cl[4*k+3] = c4.w;
            rw[4*k] = r4.x; rw[4*k+1] = r4.y; rw[4*k+2] = r4.z; rw[4*k+3] = r4.w;
            atomicAdd(&lh[c4.x >> BSHIFT], 1u);
            atomicAdd(&lh[c4.y >> BSHIFT], 1u);
            atomicAdd(&lh[c4.z >> BSHIFT], 1u);
            atomicAdd(&lh[c4.w >> BSHIFT], 1u);
        } else {
            #pragma unroll
            for (int q = 0; q < 4; ++q) {
                int e = eb + q;
                if (e < end) {
                    cl[4*k+q] = col[e];
                    rw[4*k+q] = row[e];
                    atomicAdd(&lh[cl[4*k+q] >> BSHIFT], 1u);
                } else cl[4*k+q] = -1;
            }
        }
    }
    __syncthreads();

    // wave-shuffle exclusive scan of lh[0..512) -> lbase
    int i0 = w * 128 + lane * 2;
    unsigned int a = lh[i0], b = lh[i0 + 1];
    unsigned int sum = a + b;
    unsigned int sc = sum;
    #pragma unroll
    for (int off = 1; off < 64; off <<= 1) {
        unsigned int u = __shfl_up(sc, off);
        if (lane >= off) sc += u;
    }
    if (lane == 63) swave[w] = sc;
    __syncthreads();
    unsigned int woff = 0;
    for (int k = 0; k < w; ++k) woff += swave[k];
    lbase[i0]     = (int)(woff + sc - sum);
    lbase[i0 + 1] = (int)(woff + sc - sum + a);
    __syncthreads();

    // phase 2: reserve dense global segments inside fixed-capacity regions
    for (int bb = t; bb < NBUK; bb += 256) {
        unsigned int c = lh[bb];
        int g = bb * cap + (c ? atomicAdd(&bcur[bb * PAD], (int)c) : 0);
        gbase[bb] = g;
        lh[bb] = (unsigned int)g;
    }
    __syncthreads();

    // phase 3a: scatter into LDS by rank (from registers)
    #pragma unroll
    for (int k = 0; k < 8; ++k) {
        if (cl[k] >= 0) {
            int bb = cl[k] >> BSHIFT;
            int gpos = (int)atomicAdd(&lh[bb], 1u);
            int lslot = gpos - gbase[bb] + lbase[bb];
            lpair[lslot] = ((unsigned int)(cl[k] & CMASK) << 24) | (unsigned int)rw[k];
        }
    }
    __syncthreads();

    // phase 3b: linear LDS -> coalesced global writes; bucket recovered by
    // branchless binary search over monotone lbase.
    int tilesz = end - base;
    for (int j = t; j < tilesz; j += 256) {
        int pos = 0;
        #pragma unroll
        for (int step = 256; step; step >>= 1) {
            int np = pos + step;
            if (np < MAXBUK && lbase[np] <= j) pos = np;
        }
        buf[gbase[pos] + (j - lbase[pos])] = lpair[j];
    }
}

// ---------- per-bucket fine sort (in place, 8-padded) + fused node prep ----------
__global__ void k_csort(unsigned int* __restrict__ buf, const int* __restrict__ bcur,
                        int* __restrict__ row_ptr, unsigned int* __restrict__ count,
                        const float* __restrict__ x, float* __restrict__ dinv,
                        float2* __restrict__ y, float4* __restrict__ triple,
                        int cap, int N) {
    __shared__ unsigned int lp[LCAP];
    __shared__ unsigned int lh[CPB];
    __shared__ int lofs[CPB];
    __shared__ unsigned int swave[4];
    int b = blockIdx.x;
    int t = threadIdx.x;
    int w = t >> 6, lane = t & 63;
    int c0 = b << BSHIFT;
    int s = b * cap;
    int cntb = bcur[b * PAD];
    lh[t] = 0u;
    if (b == 0 && t == 0) {                  // zero pad slots
        y[N] = make_float2(0.0f, 0.0f);
        triple[N] = make_float4(0.0f, 0.0f, 0.0f, 0.0f);
    }
    __syncthreads();
    for (int j = t; j < cntb; j += 256) {
        unsigned int u = buf[s + j];
        lp[j] = u;
        atomicAdd(&lh[u >> 24], 1u);
    }
    __syncthreads();
    unsigned int v = lh[t];
    unsigned int pv = (v + 7u) & ~7u;       // pad each col segment to multiple of 8
    unsigned int sc = pv;
    #pragma unroll
    for (int off = 1; off < 64; off <<= 1) {
        unsigned int u = __shfl_up(sc, off);
        if (lane >= off) sc += u;
    }
    if (lane == 63) swave[w] = sc;
    __syncthreads();
    unsigned int woff = 0;
    for (int k = 0; k < w; ++k) woff += swave[k];
    int excl = s + (int)(woff + sc - pv);
    int c = c0 + t;
    if (c < N) {
        row_ptr[c] = excl;
        count[c] = v;
        float dv = rsqrtf((float)v + 1.0f);
        dinv[c] = dv;
        float2 xv = ((const float2*)x)[c];
        y[c] = make_float2(dv * xv.x, dv * xv.y);
    }
    lofs[t] = excl;
    __syncthreads();
    for (int j = t; j < cntb; j += 256) {
        unsigned int u = lp[j];
        int pos = atomicAdd(&lofs[u >> 24], 1);
        buf[pos] = u & 0x00FFFFFFu;
    }
    for (unsigned int k = v; k < pv; ++k) buf[excl + k] = (unsigned int)N;
}

// ================= compute pipeline (all f32) =================

// fallback-only prep
__global__ void k_prep(const float* __restrict__ x, const unsigned int* __restrict__ count,
                       float* __restrict__ dinv, float2* __restrict__ y,
                       float4* __restrict__ triple, int N) {
    int i = blockIdx.x * blockDim.x + threadIdx.x;
    if (i == 0) {
        y[N] = make_float2(0.0f, 0.0f);
        triple[N] = make_float4(0.0f, 0.0f, 0.0f, 0.0f);
    }
    if (i >= N) return;
    float dv = rsqrtf((float)count[i] + 1.0f);
    dinv[i] = dv;
    float2 xv = ((const float2*)x)[i];
    y[i] = make_float2(dv * xv.x, dv * xv.y);
}

// layer-1 aggregation in input space: triple[i] = (dv*zx, dv*zy, dv); 8 lanes/node
__global__ void k_agg1(const int* __restrict__ row_ptr, const unsigned int* __restrict__ count,
                       const int* __restrict__ sorted_row, const float2* __restrict__ y,
                       const float* __restrict__ dinv, float4* __restrict__ triple, int N) {
    int t = threadIdx.x;
    int i = blockIdx.x * 32 + (t >> 3), l = t & 7;
    if (i >= N) return;
    int s = row_ptr[i];
    int e = s + (int)count[i];
    float zx = 0.0f, zy = 0.0f;
    for (int j = s + l; j < e; j += 8) {
        float2 yv = y[sorted_row[j]];
        zx += yv.x; zy += yv.y;
    }
    #pragma unroll
    for (int m = 4; m >= 1; m >>= 1) {
        zx += __shfl_xor(zx, m);
        zy += __shfl_xor(zy, m);
    }
    if (l == 0) {
        float2 yi = y[i];                  // self loop
        zx += yi.x; zy += yi.y;
        float dv = dinv[i];
        triple[i] = make_float4(dv * zx, dv * zy, dv, 0.0f);
    }
}

__device__ __forceinline__ float4 f4fma(float s, float4 m, float4 a) {
    return make_float4(fmaf(s, m.x, a.x), fmaf(s, m.y, a.y),
                       fmaf(s, m.z, a.z), fmaf(s, m.w, a.w));
}
__device__ __forceinline__ float4 f4relu(float4 q) {
    return make_float4(fmaxf(q.x, 0.f), fmaxf(q.y, 0.f), fmaxf(q.z, 0.f), fmaxf(q.w, 0.f));
}

// layer-2 agg + pool: 8 lanes/node; per 8-edge chunk each lane loads ONE triple,
// broadcast via sub-group shuffles (width 8) -> 8x fewer outstanding loads.
__global__ void __launch_bounds__(256)
k_agg_pool(const int* __restrict__ row_ptr, const unsigned int* __restrict__ count,
           const int* __restrict__ sorted_row, const float4* __restrict__ triple,
           const float* __restrict__ W1, const float* __restrict__ b1,
           const int* __restrict__ batch, float* __restrict__ pool,
           float* __restrict__ cnt, int N) {
    __shared__ float sh[32][FDIM];
    __shared__ int sb[32];
    int t = threadIdx.x;
    int n = t >> 3, l = t & 7;
    int i = blockIdx.x * 32 + n;
    int fa = 4 * l;
    float4 w0 = *(const float4*)(W1 + fa);
    float4 w1 = *(const float4*)(W1 + FDIM + fa);
    float4 bb = *(const float4*)(b1 + fa);
    float4 acc = make_float4(0.f, 0.f, 0.f, 0.f);
    int bt = -1;
    if (i < N) {
        float4 ts = triple[i];              // self
        float dv = ts.z;
        acc = f4fma(ts.z, f4relu(f4fma(ts.x, w0, f4fma(ts.y, w1, bb))), acc);
        int s = row_ptr[i];
        int pv = ((int)count[i] + 7) & ~7;
        for (int j = s; j < s + pv; j += 8) {
            int idx = sorted_row[j + l];
            float4 tl = triple[idx];        // one load per lane
            #pragma unroll
            for (int k = 0; k < 8; ++k) {
                float tx = __shfl(tl.x, k, 8);
                float ty = __shfl(tl.y, k, 8);
                float tz = __shfl(tl.z, k, 8);
                acc = f4fma(tz, f4relu(f4fma(tx, w0, f4fma(ty, w1, bb))), acc);
            }
        }
        acc.x *= dv; acc.y *= dv; acc.z *= dv; acc.w *= dv;
        bt = batch[i];
    }
    *(float4*)&sh[n][fa] = acc;
    if (l == 0) sb[n] = bt;
    __syncthreads();
    if (bt >= 0 && (n == 0 || sb[n - 1] != bt)) {   // segment leader
        float4 ssum = acc;
        int m = n + 1;
        for (; m < 32 && sb[m] == bt; ++m) {
            float4 o = *(const float4*)&sh[m][fa];
            ssum.x += o.x; ssum.y += o.y; ssum.z += o.z; ssum.w += o.w;
        }
        atomicAdd(&pool[bt * FDIM + fa],     ssum.x);
        atomicAdd(&pool[bt * FDIM + fa + 1], ssum.y);
        atomicAdd(&pool[bt * FDIM + fa + 2], ssum.z);
        atomicAdd(&pool[bt * FDIM + fa + 3], ssum.w);
        if (l == 0) atomicAdd(&cnt[bt], (float)(m - n));
    }
}

// out[g] = (pool[g]/cnt[g]) @ W2 + b2   (8 graphs/WG)
__global__ void k_out(const float* __restrict__ pool, const float* __restrict__ cnt,
                      const float* __restrict__ W2, const float* __restrict__ b2,
                      float* __restrict__ out, int G) {
    __shared__ float sW[FDIM * FDIM];
    int t = threadIdx.x;
    for (int k = t; k < FDIM * FDIM; k += 256) sW[k] = W2[k];
    __syncthreads();
    int g = blockIdx.x * 8 + (t >> 5), f = t & 31;
    if (g >= G) return;
    float c = cnt[g];
    float o = 0.0f;
    if (c > 0.0f) {
        float s = 0.0f;
        #pragma unroll
        for (int k = 0; k < FDIM; ++k) s = fmaf(pool[g * FDIM + k], sW[k * FDIM + f], s);
        o = fmaf(s, 1.0f / c, b2[f]);
    }
    out[g * FDIM + f] = o;
}

// ================= compact correct-but-slow fallback (atomic path) =================

__global__ void k_fhist(const int* __restrict__ col, unsigned int* __restrict__ count, int E) {
    int i = blockIdx.x * blockDim.x + threadIdx.x;
    if (i < E) atomicAdd(&count[col[i]], 1u);
}
__global__ void k_fsc2(const int* __restrict__ row, const int* __restrict__ col,
                       const float2* __restrict__ y, float* __restrict__ z, int E) {
    int e = blockIdx.x * blockDim.x + threadIdx.x;
    if (e >= E) return;
    float2 yv = y[row[e]];
    int c = col[e];
    atomicAdd(&z[2 * c],     yv.x);
    atomicAdd(&z[2 * c + 1], yv.y);
}
__global__ void k_fmkt(const float* __restrict__ z, const float2* __restrict__ y,
                       const float* __restrict__ dinv, float4* __restrict__ triple, int N) {
    int i = blockIdx.x * blockDim.x + threadIdx.x;
    if (i >= N) return;
    float dv = dinv[i];
    float2 yi = y[i];
    triple[i] = make_float4(dv * (z[2 * i] + yi.x), dv * (z[2 * i + 1] + yi.y), dv, 0.0f);
}
__global__ void k_fsc32(const int* __restrict__ row, const int* __restrict__ col,
                        const float4* __restrict__ triple, const float* __restrict__ W1,
                        const float* __restrict__ b1, float* __restrict__ v, int total) {
    int idx = blockIdx.x * blockDim.x + threadIdx.x;
    if (idx >= total) return;
    int e = idx >> 5, f = idx & 31;
    float4 tr = triple[row[e]];
    float u = tr.z * fmaxf(fmaf(tr.x, W1[f], fmaf(tr.y, W1[FDIM + f], b1[f])), 0.0f);
    atomicAdd(&v[col[e] * FDIM + f], u);
}
__global__ void k_ffin(const float4* __restrict__ triple, const float* __restrict__ v,
                       const float* __restrict__ W1, const float* __restrict__ b1,
                       const int* __restrict__ batch, float* __restrict__ pool,
                       float* __restrict__ cnt, int N) {
    int idx = blockIdx.x * blockDim.x + threadIdx.x;
    int i = idx >> 5, f = idx & 31;
    if (i >= N) return;
    float4 tr = triple[i];
    float u = tr.z * fmaxf(fmaf(tr.x, W1[f], fmaf(tr.y, W1[FDIM + f], b1[f])), 0.0f);
    float w = tr.z * (u + v[i * FDIM + f]);
    int b = batch[i];
    atomicAdd(&pool[b * FDIM + f], w);
    if (f == 0) atomicAdd(&cnt[b], 1.0f);
}

extern "C" void kernel_launch(void* const* d_in, const int* in_sizes, int n_in,
                              void* d_out, int out_size, void* d_ws, size_t ws_size,
                              hipStream_t stream) {
    const float* x   = (const float*)d_in[0];
    const int*   ei  = (const int*)d_in[1];
    const int* batch = (const int*)d_in[2];
    const float* W1  = (const float*)d_in[4];
    const float* b1  = (const float*)d_in[5];
    const float* W2  = (const float*)d_in[6];
    const float* b2  = (const float*)d_in[7];
    float* out = (float*)d_out;

    int N = in_sizes[0] / 2;
    int E = in_sizes[1] / 2;
    int G = out_size / FDIM;

    const int* row = ei;
    const int* col = ei + E;

    int NB = (N + 255) / 256;
    int NBUK = (N + CMASK) >> BSHIFT;

    // fixed bucket capacity: avg + 12.5% + 2048, rounded to 8
    int capBase = (E + NBUK - 1) / NBUK;
    int cap = capBase + capBase / 8 + 2048;
    cap = (cap + 7) & ~7;

    // primary layout (u32 units)
    size_t off = 0;
    size_t o_bcur = off;  off += (size_t)NBUK * PAD;
    size_t o_cnt  = off;  off += N;           // count
    size_t o_rp   = off;  off += N;           // row_ptr
    size_t o_dv   = off;  off += N;           // dinv
    size_t o_y    = off;  off += 2ull * (N + 1);
    off = (off + 3) & ~(size_t)3;             // 16B align
    size_t o_tr   = off;  off += 4ull * (N + 1);
    size_t o_buf  = off;  off += (size_t)NBUK * cap;
    size_t o_pool = off;  off += 32ull * G;
    size_t o_cg   = off;  off += G;
    size_t elemsNew = off;

    unsigned int* W = (unsigned int*)d_ws;

    if (ws_size >= elemsNew * 4 && N < (1 << 24) && NBUK <= MAXBUK && cap <= LCAP) {
        int* bcur           = (int*)(W + o_bcur);
        unsigned int* count = (unsigned int*)(W + o_cnt);
        int* row_ptr        = (int*)(W + o_rp);
        float* dinv         = (float*)(W + o_dv);
        float2* y           = (float2*)(W + o_y);
        float4* triple      = (float4*)(W + o_tr);
        unsigned int* buf   = W + o_buf;      // pairs, then sorted_row in place
        float* pool         = (float*)(W + o_pool);
        float* cntg         = (float*)(W + o_cg);

        int nb = NBUK * PAD;
        int np = G * FDIM + G;
        int zgrid = (max(nb, np) + 255) / 256;
        k_zero<<<zgrid, 256, 0, stream>>>(bcur, pool, nb, np);

        k_binsort<<<(E + BNT - 1) / BNT, 256, 0, stream>>>(row, col, bcur, buf, E, cap, NBUK);
        k_csort<<<NBUK, 256, 0, stream>>>(buf, bcur, row_ptr, count, x, dinv, y, triple, cap, N);

        k_agg1<<<(N + 31) / 32, 256, 0, stream>>>(row_ptr, count, (const int*)buf, y, dinv,
                                                  triple, N);
        k_agg_pool<<<(N + 31) / 32, 256, 0, stream>>>(row_ptr, count, (const int*)buf, triple,
                                                      W1, b1, batch, pool, cntg, N);
        k_out<<<(G + 7) / 8, 256, 0, stream>>>(pool, cntg, W2, b2, out, G);
    } else {
        // compact fallback: atomic scatter (correct, slow; not expected to run)
        unsigned int* count = (unsigned int*)d_ws;             // N
        float* dinv         = (float*)(count + N);             // N
        float2* y           = (float2*)(dinv + N);             // N+1
        float* z            = (float*)(y + N + 1);             // 2N
        size_t toff = ((size_t)(z + 2 * N - (float*)d_ws) + 3) & ~(size_t)3;
        float4* triple      = (float4*)((float*)d_ws + toff);  // N+1
        float* v            = (float*)(triple + N + 1);        // 32N
        float* pool         = v + 32ull * N;                   // 32G
        float* cntg         = pool + 32ull * G;                // G

        hipMemsetAsync(count, 0, (size_t)N * 4, stream);
        hipMemsetAsync(z, 0, (size_t)N * 8, stream);
        hipMemsetAsync(v, 0, (size_t)N * FDIM * 4, stream);
        hipMemsetAsync(pool, 0, (size_t)(G * FDIM + G) * 4, stream);

        k_fhist<<<(E + 255) / 256, 256, 0, stream>>>(col, count, E);
        k_prep<<<NB, 256, 0, stream>>>(x, count, dinv, y, triple, N);
        k_fsc2<<<(E + 255) / 256, 256, 0, stream>>>(row, col, y, z, E);
        k_fmkt<<<NB, 256, 0, stream>>>(z, y, dinv, triple, N);
        int ts = E * FDIM;
        k_fsc32<<<(ts + 255) / 256, 256, 0, stream>>>(row, col, triple, W1, b1, v, ts);
        k_ffin<<<(N * FDIM + 255) / 256, 256, 0, stream>>>(triple, v, W1, b1, batch, pool, cntg, N);
        k_out<<<(G + 7) / 8, 256, 0, stream>>>(pool, cntg, W2, b2, out, G);
    }
}

// Round 16
// 122.694 us; speedup vs baseline: 1.2675x; 1.2675x over previous
//
#include <hip/hip_runtime.h>

#define FDIM 32
#define BSHIFT 8                 // 256 cols per bucket
#define CPB (1 << BSHIFT)
#define CMASK (CPB - 1)
#define PAD 16                   // cursor stride: 16 u32 = 64B (one cacheline)
#define MAXBUK 512
#define BNT 8192                 // binsort tile (edges per WG, 16/thread @512)
#define BTHREADS 512
#define LCAP 12288               // csort LDS staging capacity (48 KB)
#define SENT 0xFFFFFFFFu

// ---------- one-launch zero of bcur + pool + cnt ----------
__global__ void k_zero(int* __restrict__ bcur, float* __restrict__ pool, int nb, int np) {
    int i = blockIdx.x * blockDim.x + threadIdx.x;
    if (i < nb) bcur[i] = 0;
    if (i < np) pool[i] = 0.0f;
}

// ---------- LDS-staged binning; 64B-aligned sentinel-padded segments ----------
// pack: (col & 255) << 24 | row   (needs N < 2^24)
__global__ void __launch_bounds__(BTHREADS)
k_binsort(const int* __restrict__ row, const int* __restrict__ col,
          int* bcur, unsigned int* __restrict__ buf, int E, int cap, int NBUK) {
    __shared__ unsigned int lh[MAXBUK];      // hist -> global cursor
    __shared__ int lbase[MAXBUK];            // local exclusive base (monotone)
    __shared__ int gbase[MAXBUK];            // global segment base (16-aligned)
    __shared__ unsigned int swave[4];
    __shared__ unsigned int lpair[BNT];      // staged packed pairs (rank order)
    int t = threadIdx.x;
    int w = t >> 6, lane = t & 63;
    int base = blockIdx.x * BNT;
    int end = min(base + BNT, E);
    int tilesz = end - base;

    if (t < MAXBUK) lh[t] = 0u;
    __syncthreads();

    // phase 1: tile histogram; int4-vectorized (col,row) loads cached in registers.
    int cl[16], rw[16];
    #pragma unroll
    for (int k = 0; k < 4; ++k) {
        int e4 = (base >> 2) + k * BTHREADS + t;  // edge block [4*e4, 4*e4+4)
        int eb = 4 * e4;
        if (eb + 3 < end) {
            int4 c4 = *(const int4*)(col + eb);
            int4 r4 = *(const int4*)(row + eb);
            cl[4*k] = c4.x; cl[4*k+1] = c4.y; cl[4*k+2] = c4.z; cl[4*k+3] = c4.w;
            rw[4*k] = r4.x; rw[4*k+1] = r4.y; rw[4*k+2] = r4.z; rw[4*k+3] = r4.w;
            atomicAdd(&lh[c4.x >> BSHIFT], 1u);
            atomicAdd(&lh[c4.y >> BSHIFT], 1u);
            atomicAdd(&lh[c4.z >> BSHIFT], 1u);
            atomicAdd(&lh[c4.w >> BSHIFT], 1u);
        } else {
            #pragma unroll
            for (int q = 0; q < 4; ++q) {
                int e = eb + q;
                if (e < end) {
                    cl[4*k+q] = col[e];
                    rw[4*k+q] = row[e];
                    atomicAdd(&lh[cl[4*k+q] >> BSHIFT], 1u);
                } else cl[4*k+q] = -1;
            }
        }
    }
    __syncthreads();

    // wave-shuffle exclusive scan of lh[0..512) -> lbase (waves 0-3 only)
    if (w < 4) {
        int i0 = w * 128 + lane * 2;
        unsigned int a = lh[i0], b = lh[i0 + 1];
        unsigned int sum = a + b;
        unsigned int sc = sum;
        #pragma unroll
        for (int off = 1; off < 64; off <<= 1) {
            unsigned int u = __shfl_up(sc, off);
            if (lane >= off) sc += u;
        }
        if (lane == 63) swave[w] = sc;
        __syncthreads();
        unsigned int woff = 0;
        for (int k = 0; k < w; ++k) woff += swave[k];
        lbase[i0]     = (int)(woff + sc - sum);
        lbase[i0 + 1] = (int)(woff + sc - sum + a);
    } else {
        __syncthreads();
    }
    __syncthreads();

    // phase 2: reserve 16-aligned global segments inside fixed-capacity regions
    for (int bb = t; bb < NBUK; bb += BTHREADS) {
        unsigned int c = lh[bb];
        unsigned int cp = (c + 15u) & ~15u;
        int g = bb * cap + (cp ? atomicAdd(&bcur[bb * PAD], (int)cp) : 0);
        gbase[bb] = g;
        lh[bb] = (unsigned int)g;
    }
    __syncthreads();

    // phase 3a: scatter into LDS by rank (from registers)
    #pragma unroll
    for (int k = 0; k < 16; ++k) {
        if (cl[k] >= 0) {
            int bb = cl[k] >> BSHIFT;
            int gpos = (int)atomicAdd(&lh[bb], 1u);
            int lslot = gpos - gbase[bb] + lbase[bb];
            lpair[lslot] = ((unsigned int)(cl[k] & CMASK) << 24) | (unsigned int)rw[k];
        }
    }
    __syncthreads();

    // phase 3b: linear LDS -> coalesced, exclusively-owned global segment writes
    for (int j = t; j < tilesz; j += BTHREADS) {
        int pos = 0;
        #pragma unroll
        for (int step = 256; step; step >>= 1) {
            int np = pos + step;
            if (np < MAXBUK && lbase[np] <= j) pos = np;
        }
        buf[gbase[pos] + (j - lbase[pos])] = lpair[j];
    }

    // sentinel fill of segment pads (tail lines stay single-writer)
    for (int bb = t; bb < NBUK; bb += BTHREADS) {
        int lb = lbase[bb];
        int cend = (bb + 1 < NBUK) ? lbase[bb + 1] : tilesz;
        int c = cend - lb;
        int cp = (c + 15) & ~15;
        int g = gbase[bb];
        for (int k = c; k < cp; ++k) buf[g + k] = SENT;
    }
}

// ---------- per-bucket fine sort (in place, 8-padded), sentinel-aware, + fused prep ----------
__global__ void k_csort(unsigned int* __restrict__ buf, const int* __restrict__ bcur,
                        int* __restrict__ row_ptr, unsigned int* __restrict__ count,
                        const float* __restrict__ x, float* __restrict__ dinv,
                        float2* __restrict__ y, float4* __restrict__ triple,
                        int cap, int N) {
    __shared__ unsigned int lp[LCAP];
    __shared__ unsigned int lh[CPB];
    __shared__ int lofs[CPB];
    __shared__ unsigned int swave[4];
    int b = blockIdx.x;
    int t = threadIdx.x;
    int w = t >> 6, lane = t & 63;
    int c0 = b << BSHIFT;
    int s = b * cap;
    int cntb = bcur[b * PAD];                // padded size incl sentinels
    lh[t] = 0u;
    if (b == 0 && t == 0) {                  // zero pad slots
        y[N] = make_float2(0.0f, 0.0f);
        triple[N] = make_float4(0.0f, 0.0f, 0.0f, 0.0f);
    }
    __syncthreads();
    for (int j = t; j < cntb; j += 256) {
        unsigned int u = buf[s + j];
        lp[j] = u;
        if (u != SENT) atomicAdd(&lh[u >> 24], 1u);
    }
    __syncthreads();
    unsigned int v = lh[t];
    unsigned int pv = (v + 7u) & ~7u;       // pad each col segment to multiple of 8
    unsigned int sc = pv;
    #pragma unroll
    for (int off = 1; off < 64; off <<= 1) {
        unsigned int u = __shfl_up(sc, off);
        if (lane >= off) sc += u;
    }
    if (lane == 63) swave[w] = sc;
    __syncthreads();
    unsigned int woff = 0;
    for (int k = 0; k < w; ++k) woff += swave[k];
    int excl = s + (int)(woff + sc - pv);
    int c = c0 + t;
    if (c < N) {
        row_ptr[c] = excl;
        count[c] = v;
        float dv = rsqrtf((float)v + 1.0f);
        dinv[c] = dv;
        float2 xv = ((const float2*)x)[c];
        y[c] = make_float2(dv * xv.x, dv * xv.y);
    }
    lofs[t] = excl;
    __syncthreads();
    for (int j = t; j < cntb; j += 256) {
        unsigned int u = lp[j];
        if (u != SENT) {
            int pos = atomicAdd(&lofs[u >> 24], 1);
            buf[pos] = u & 0x00FFFFFFu;
        }
    }
    for (unsigned int k = v; k < pv; ++k) buf[excl + k] = (unsigned int)N;
}

// ================= compute pipeline (all f32) =================

// fallback-only prep
__global__ void k_prep(const float* __restrict__ x, const unsigned int* __restrict__ count,
                       float* __restrict__ dinv, float2* __restrict__ y,
                       float4* __restrict__ triple, int N) {
    int i = blockIdx.x * blockDim.x + threadIdx.x;
    if (i == 0) {
        y[N] = make_float2(0.0f, 0.0f);
        triple[N] = make_float4(0.0f, 0.0f, 0.0f, 0.0f);
    }
    if (i >= N) return;
    float dv = rsqrtf((float)count[i] + 1.0f);
    dinv[i] = dv;
    float2 xv = ((const float2*)x)[i];
    y[i] = make_float2(dv * xv.x, dv * xv.y);
}

// layer-1 aggregation in input space: triple[i] = (dv*zx, dv*zy, dv); 8 lanes/node
__global__ void k_agg1(const int* __restrict__ row_ptr, const unsigned int* __restrict__ count,
                       const int* __restrict__ sorted_row, const float2* __restrict__ y,
                       const float* __restrict__ dinv, float4* __restrict__ triple, int N) {
    int t = threadIdx.x;
    int i = blockIdx.x * 32 + (t >> 3), l = t & 7;
    if (i >= N) return;
    int s = row_ptr[i];
    int e = s + (int)count[i];
    float zx = 0.0f, zy = 0.0f;
    for (int j = s + l; j < e; j += 8) {
        float2 yv = y[sorted_row[j]];
        zx += yv.x; zy += yv.y;
    }
    #pragma unroll
    for (int m = 4; m >= 1; m >>= 1) {
        zx += __shfl_xor(zx, m);
        zy += __shfl_xor(zy, m);
    }
    if (l == 0) {
        float2 yi = y[i];                  // self loop
        zx += yi.x; zy += yi.y;
        float dv = dinv[i];
        triple[i] = make_float4(dv * zx, dv * zy, dv, 0.0f);
    }
}

__device__ __forceinline__ float4 f4fma(float s, float4 m, float4 a) {
    return make_float4(fmaf(s, m.x, a.x), fmaf(s, m.y, a.y),
                       fmaf(s, m.z, a.z), fmaf(s, m.w, a.w));
}
__device__ __forceinline__ float4 f4relu(float4 q) {
    return make_float4(fmaxf(q.x, 0.f), fmaxf(q.y, 0.f), fmaxf(q.z, 0.f), fmaxf(q.w, 0.f));
}

// layer-2 agg + pool: 8 lanes/node (4 features/lane as float4), unroll 8. (R13-proven)
__global__ void __launch_bounds__(256)
k_agg_pool(const int* __restrict__ row_ptr, const unsigned int* __restrict__ count,
           const int* __restrict__ sorted_row, const float4* __restrict__ triple,
           const float* __restrict__ W1, const float* __restrict__ b1,
           const int* __restrict__ batch, float* __restrict__ pool,
           float* __restrict__ cnt, int N) {
    __shared__ float sh[32][FDIM];
    __shared__ int sb[32];
    int t = threadIdx.x;
    int n = t >> 3, l = t & 7;
    int i = blockIdx.x * 32 + n;
    int fa = 4 * l;
    float4 w0 = *(const float4*)(W1 + fa);
    float4 w1 = *(const float4*)(W1 + FDIM + fa);
    float4 bb = *(const float4*)(b1 + fa);
    float4 acc = make_float4(0.f, 0.f, 0.f, 0.f);
    int bt = -1;
    if (i < N) {
        float4 ts = triple[i];              // self
        float dv = ts.z;
        acc = f4fma(ts.z, f4relu(f4fma(ts.x, w0, f4fma(ts.y, w1, bb))), acc);
        int s = row_ptr[i];
        int pv = ((int)count[i] + 7) & ~7;
        for (int j = s; j < s + pv; j += 8) {
            int4 ra = *(const int4*)(sorted_row + j);
            int4 rb = *(const int4*)(sorted_row + j + 4);
            float4 t0 = triple[ra.x], t1 = triple[ra.y], t2 = triple[ra.z], t3 = triple[ra.w];
            float4 t4 = triple[rb.x], t5 = triple[rb.y], t6 = triple[rb.z], t7 = triple[rb.w];
            acc = f4fma(t0.z, f4relu(f4fma(t0.x, w0, f4fma(t0.y, w1, bb))), acc);
            acc = f4fma(t1.z, f4relu(f4fma(t1.x, w0, f4fma(t1.y, w1, bb))), acc);
            acc = f4fma(t2.z, f4relu(f4fma(t2.x, w0, f4fma(t2.y, w1, bb))), acc);
            acc = f4fma(t3.z, f4relu(f4fma(t3.x, w0, f4fma(t3.y, w1, bb))), acc);
            acc = f4fma(t4.z, f4relu(f4fma(t4.x, w0, f4fma(t4.y, w1, bb))), acc);
            acc = f4fma(t5.z, f4relu(f4fma(t5.x, w0, f4fma(t5.y, w1, bb))), acc);
            acc = f4fma(t6.z, f4relu(f4fma(t6.x, w0, f4fma(t6.y, w1, bb))), acc);
            acc = f4fma(t7.z, f4relu(f4fma(t7.x, w0, f4fma(t7.y, w1, bb))), acc);
        }
        acc.x *= dv; acc.y *= dv; acc.z *= dv; acc.w *= dv;
        bt = batch[i];
    }
    *(float4*)&sh[n][fa] = acc;
    if (l == 0) sb[n] = bt;
    __syncthreads();
    if (bt >= 0 && (n == 0 || sb[n - 1] != bt)) {   // segment leader
        float4 ssum = acc;
        int m = n + 1;
        for (; m < 32 && sb[m] == bt; ++m) {
            float4 o = *(const float4*)&sh[m][fa];
            ssum.x += o.x; ssum.y += o.y; ssum.z += o.z; ssum.w += o.w;
        }
        atomicAdd(&pool[bt * FDIM + fa],     ssum.x);
        atomicAdd(&pool[bt * FDIM + fa + 1], ssum.y);
        atomicAdd(&pool[bt * FDIM + fa + 2], ssum.z);
        atomicAdd(&pool[bt * FDIM + fa + 3], ssum.w);
        if (l == 0) atomicAdd(&cnt[bt], (float)(m - n));
    }
}

// out[g] = (pool[g]/cnt[g]) @ W2 + b2   (8 graphs/WG)
__global__ void k_out(const float* __restrict__ pool, const float* __restrict__ cnt,
                      const float* __restrict__ W2, const float* __restrict__ b2,
                      float* __restrict__ out, int G) {
    __shared__ float sW[FDIM * FDIM];
    int t = threadIdx.x;
    for (int k = t; k < FDIM * FDIM; k += 256) sW[k] = W2[k];
    __syncthreads();
    int g = blockIdx.x * 8 + (t >> 5), f = t & 31;
    if (g >= G) return;
    float c = cnt[g];
    float o = 0.0f;
    if (c > 0.0f) {
        float s = 0.0f;
        #pragma unroll
        for (int k = 0; k < FDIM; ++k) s = fmaf(pool[g * FDIM + k], sW[k * FDIM + f], s);
        o = fmaf(s, 1.0f / c, b2[f]);
    }
    out[g * FDIM + f] = o;
}

// ================= compact correct-but-slow fallback (atomic path) =================

__global__ void k_fhist(const int* __restrict__ col, unsigned int* __restrict__ count, int E) {
    int i = blockIdx.x * blockDim.x + threadIdx.x;
    if (i < E) atomicAdd(&count[col[i]], 1u);
}
__global__ void k_fsc2(const int* __restrict__ row, const int* __restrict__ col,
                       const float2* __restrict__ y, float* __restrict__ z, int E) {
    int e = blockIdx.x * blockDim.x + threadIdx.x;
    if (e >= E) return;
    float2 yv = y[row[e]];
    int c = col[e];
    atomicAdd(&z[2 * c],     yv.x);
    atomicAdd(&z[2 * c + 1], yv.y);
}
__global__ void k_fmkt(const float* __restrict__ z, const float2* __restrict__ y,
                       const float* __restrict__ dinv, float4* __restrict__ triple, int N) {
    int i = blockIdx.x * blockDim.x + threadIdx.x;
    if (i >= N) return;
    float dv = dinv[i];
    float2 yi = y[i];
    triple[i] = make_float4(dv * (z[2 * i] + yi.x), dv * (z[2 * i + 1] + yi.y), dv, 0.0f);
}
__global__ void k_fsc32(const int* __restrict__ row, const int* __restrict__ col,
                        const float4* __restrict__ triple, const float* __restrict__ W1,
                        const float* __restrict__ b1, float* __restrict__ v, int total) {
    int idx = blockIdx.x * blockDim.x + threadIdx.x;
    if (idx >= total) return;
    int e = idx >> 5, f = idx & 31;
    float4 tr = triple[row[e]];
    float u = tr.z * fmaxf(fmaf(tr.x, W1[f], fmaf(tr.y, W1[FDIM + f], b1[f])), 0.0f);
    atomicAdd(&v[col[e] * FDIM + f], u);
}
__global__ void k_ffin(const float4* __restrict__ triple, const float* __restrict__ v,
                       const float* __restrict__ W1, const float* __restrict__ b1,
                       const int* __restrict__ batch, float* __restrict__ pool,
                       float* __restrict__ cnt, int N) {
    int idx = blockIdx.x * blockDim.x + threadIdx.x;
    int i = idx >> 5, f = idx & 31;
    if (i >= N) return;
    float4 tr = triple[i];
    float u = tr.z * fmaxf(fmaf(tr.x, W1[f], fmaf(tr.y, W1[FDIM + f], b1[f])), 0.0f);
    float w = tr.z * (u + v[i * FDIM + f]);
    int b = batch[i];
    atomicAdd(&pool[b * FDIM + f], w);
    if (f == 0) atomicAdd(&cnt[b], 1.0f);
}

extern "C" void kernel_launch(void* const* d_in, const int* in_sizes, int n_in,
                              void* d_out, int out_size, void* d_ws, size_t ws_size,
                              hipStream_t stream) {
    const float* x   = (const float*)d_in[0];
    const int*   ei  = (const int*)d_in[1];
    const int* batch = (const int*)d_in[2];
    const float* W1  = (const float*)d_in[4];
    const float* b1  = (const float*)d_in[5];
    const float* W2  = (const float*)d_in[6];
    const float* b2  = (const float*)d_in[7];
    float* out = (float*)d_out;

    int N = in_sizes[0] / 2;
    int E = in_sizes[1] / 2;
    int G = out_size / FDIM;

    const int* row = ei;
    const int* col = ei + E;

    int NB = (N + 255) / 256;
    int NBUK = (N + CMASK) >> BSHIFT;
    int ntiles = (E + BNT - 1) / BNT;

    // fixed bucket capacity: payload mean + per-segment pad mean (~8) + 5-sigma slack
    int capBase = (E + NBUK - 1) / NBUK;
    int cap = capBase + ntiles * 8 + 512;
    cap = (cap + 15) & ~15;

    // primary layout (u32 units)
    size_t off = 0;
    size_t o_bcur = off;  off += (size_t)NBUK * PAD;
    size_t o_cnt  = off;  off += N;           // count
    size_t o_rp   = off;  off += N;           // row_ptr
    size_t o_dv   = off;  off += N;           // dinv
    size_t o_y    = off;  off += 2ull * (N + 1);
    off = (off + 3) & ~(size_t)3;             // 16B align
    size_t o_tr   = off;  off += 4ull * (N + 1);
    size_t o_buf  = off;  off += (size_t)NBUK * cap;
    size_t o_pool = off;  off += 32ull * G;
    size_t o_cg   = off;  off += G;
    size_t elemsNew = off;

    unsigned int* W = (unsigned int*)d_ws;

    if (ws_size >= elemsNew * 4 && N < (1 << 24) && NBUK <= MAXBUK && cap <= LCAP) {
        int* bcur           = (int*)(W + o_bcur);
        unsigned int* count = (unsigned int*)(W + o_cnt);
        int* row_ptr        = (int*)(W + o_rp);
        float* dinv         = (float*)(W + o_dv);
        float2* y           = (float2*)(W + o_y);
        float4* triple      = (float4*)(W + o_tr);
        unsigned int* buf   = W + o_buf;      // pairs, then sorted_row in place
        float* pool         = (float*)(W + o_pool);
        float* cntg         = (float*)(W + o_cg);

        int nb = NBUK * PAD;
        int np = G * FDIM + G;
        int zgrid = (max(nb, np) + 255) / 256;
        k_zero<<<zgrid, 256, 0, stream>>>(bcur, pool, nb, np);

        k_binsort<<<ntiles, BTHREADS, 0, stream>>>(row, col, bcur, buf, E, cap, NBUK);
        k_csort<<<NBUK, 256, 0, stream>>>(buf, bcur, row_ptr, count, x, dinv, y, triple, cap, N);

        k_agg1<<<(N + 31) / 32, 256, 0, stream>>>(row_ptr, count, (const int*)buf, y, dinv,
                                                  triple, N);
        k_agg_pool<<<(N + 31) / 32, 256, 0, stream>>>(row_ptr, count, (const int*)buf, triple,
                                                      W1, b1, batch, pool, cntg, N);
        k_out<<<(G + 7) / 8, 256, 0, stream>>>(pool, cntg, W2, b2, out, G);
    } else {
        // compact fallback: atomic scatter (correct, slow; not expected to run)
        unsigned int* count = (unsigned int*)d_ws;             // N
        float* dinv         = (float*)(count + N);             // N
        float2* y           = (float2*)(dinv + N);             // N+1
        float* z            = (float*)(y + N + 1);             // 2N
        size_t toff = ((size_t)(z + 2 * N - (float*)d_ws) + 3) & ~(size_t)3;
        float4* triple      = (float4*)((float*)d_ws + toff);  // N+1
        float* v            = (float*)(triple + N + 1);        // 32N
        float* pool         = v + 32ull * N;                   // 32G
        float* cntg         = pool + 32ull * G;                // G

        hipMemsetAsync(count, 0, (size_t)N * 4, stream);
        hipMemsetAsync(z, 0, (size_t)N * 8, stream);
        hipMemsetAsync(v, 0, (size_t)N * FDIM * 4, stream);
        hipMemsetAsync(pool, 0, (size_t)(G * FDIM + G) * 4, stream);

        k_fhist<<<(E + 255) / 256, 256, 0, stream>>>(col, count, E);
        k_prep<<<NB, 256, 0, stream>>>(x, count, dinv, y, triple, N);
        k_fsc2<<<(E + 255) / 256, 256, 0, stream>>>(row, col, y, z, E);
        k_fmkt<<<NB, 256, 0, stream>>>(z, y, dinv, triple, N);
        int ts = E * FDIM;
        k_fsc32<<<(ts + 255) / 256, 256, 0, stream>>>(row, col, triple, W1, b1, v, ts);
        k_ffin<<<(N * FDIM + 255) / 256, 256, 0, stream>>>(triple, v, W1, b1, batch, pool, cntg, N);
        k_out<<<(G + 7) / 8, 256, 0, stream>>>(pool, cntg, W2, b2, out, G);
    }
}

// Round 17
// 119.967 us; speedup vs baseline: 1.2963x; 1.0227x over previous
//
#include <hip/hip_runtime.h>

#define FDIM 32
#define BSHIFT 8                 // 256 cols per bucket
#define CPB (1 << BSHIFT)
#define CMASK (CPB - 1)
#define PAD 16                   // cursor stride: 16 u32 = 64B (one cacheline)
#define MAXBUK 512
#define BNT 8192                 // binsort tile (edges per WG, 16/thread @512)
#define BTHREADS 512
#define CTHREADS 512
#define LCAP 13312               // csort LDS staging capacity (52 KB)
#define SENT 0xFFFFFFFFu

// ---------- one-launch zero of bcur + pool + cnt ----------
__global__ void k_zero(int* __restrict__ bcur, float* __restrict__ pool, int nb, int np) {
    int i = blockIdx.x * blockDim.x + threadIdx.x;
    if (i < nb) bcur[i] = 0;
    if (i < np) pool[i] = 0.0f;
}

// ---------- LDS-staged binning; 64B-aligned sentinel-padded segments ----------
// pack: (col & 255) << 24 | row   (needs N < 2^24)
__global__ void __launch_bounds__(BTHREADS)
k_binsort(const int* __restrict__ row, const int* __restrict__ col,
          int* bcur, unsigned int* __restrict__ buf, int E, int cap, int NBUK) {
    __shared__ unsigned int lh[MAXBUK];      // hist -> global cursor
    __shared__ int lbase[MAXBUK];            // local exclusive base (monotone)
    __shared__ int gbase[MAXBUK];            // global segment base (16-aligned)
    __shared__ unsigned int swave[4];
    __shared__ unsigned int lpair[BNT];      // staged packed pairs (rank order)
    int t = threadIdx.x;
    int w = t >> 6, lane = t & 63;
    int base = blockIdx.x * BNT;
    int end = min(base + BNT, E);
    int tilesz = end - base;

    if (t < MAXBUK) lh[t] = 0u;
    __syncthreads();

    // phase 1: tile histogram; int4-vectorized (col,row) loads cached in registers.
    int cl[16], rw[16];
    #pragma unroll
    for (int k = 0; k < 4; ++k) {
        int e4 = (base >> 2) + k * BTHREADS + t;  // edge block [4*e4, 4*e4+4)
        int eb = 4 * e4;
        if (eb + 3 < end) {
            int4 c4 = *(const int4*)(col + eb);
            int4 r4 = *(const int4*)(row + eb);
            cl[4*k] = c4.x; cl[4*k+1] = c4.y; cl[4*k+2] = c4.z; cl[4*k+3] = c4.w;
            rw[4*k] = r4.x; rw[4*k+1] = r4.y; rw[4*k+2] = r4.z; rw[4*k+3] = r4.w;
            atomicAdd(&lh[c4.x >> BSHIFT], 1u);
            atomicAdd(&lh[c4.y >> BSHIFT], 1u);
            atomicAdd(&lh[c4.z >> BSHIFT], 1u);
            atomicAdd(&lh[c4.w >> BSHIFT], 1u);
        } else {
            #pragma unroll
            for (int q = 0; q < 4; ++q) {
                int e = eb + q;
                if (e < end) {
                    cl[4*k+q] = col[e];
                    rw[4*k+q] = row[e];
                    atomicAdd(&lh[cl[4*k+q] >> BSHIFT], 1u);
                } else cl[4*k+q] = -1;
            }
        }
    }
    __syncthreads();

    // wave-shuffle exclusive scan of lh[0..512) -> lbase (waves 0-3 only)
    if (w < 4) {
        int i0 = w * 128 + lane * 2;
        unsigned int a = lh[i0], b = lh[i0 + 1];
        unsigned int sum = a + b;
        unsigned int sc = sum;
        #pragma unroll
        for (int off = 1; off < 64; off <<= 1) {
            unsigned int u = __shfl_up(sc, off);
            if (lane >= off) sc += u;
        }
        if (lane == 63) swave[w] = sc;
        __syncthreads();
        unsigned int woff = 0;
        for (int k = 0; k < w; ++k) woff += swave[k];
        lbase[i0]     = (int)(woff + sc - sum);
        lbase[i0 + 1] = (int)(woff + sc - sum + a);
    } else {
        __syncthreads();
    }
    __syncthreads();

    // phase 2: reserve 16-aligned global segments inside fixed-capacity regions
    for (int bb = t; bb < NBUK; bb += BTHREADS) {
        unsigned int c = lh[bb];
        unsigned int cp = (c + 15u) & ~15u;
        int g = bb * cap + (cp ? atomicAdd(&bcur[bb * PAD], (int)cp) : 0);
        gbase[bb] = g;
        lh[bb] = (unsigned int)g;
    }
    __syncthreads();

    // phase 3a: scatter into LDS by rank (from registers)
    #pragma unroll
    for (int k = 0; k < 16; ++k) {
        if (cl[k] >= 0) {
            int bb = cl[k] >> BSHIFT;
            int gpos = (int)atomicAdd(&lh[bb], 1u);
            int lslot = gpos - gbase[bb] + lbase[bb];
            lpair[lslot] = ((unsigned int)(cl[k] & CMASK) << 24) | (unsigned int)rw[k];
        }
    }
    __syncthreads();

    // phase 3b: linear LDS -> coalesced, exclusively-owned global segment writes
    for (int j = t; j < tilesz; j += BTHREADS) {
        int pos = 0;
        #pragma unroll
        for (int step = 256; step; step >>= 1) {
            int np = pos + step;
            if (np < MAXBUK && lbase[np] <= j) pos = np;
        }
        buf[gbase[pos] + (j - lbase[pos])] = lpair[j];
    }

    // sentinel fill of segment pads (tail lines stay single-writer)
    for (int bb = t; bb < NBUK; bb += BTHREADS) {
        int lb = lbase[bb];
        int cend = (bb + 1 < NBUK) ? lbase[bb + 1] : tilesz;
        int c = cend - lb;
        int cp = (c + 15) & ~15;
        int g = gbase[bb];
        for (int k = c; k < cp; ++k) buf[g + k] = SENT;
    }
}

// ---------- per-bucket fine sort (in place, 8-padded), sentinel-aware, + fused prep ----------
__global__ void __launch_bounds__(CTHREADS)
k_csort(unsigned int* __restrict__ buf, const int* __restrict__ bcur,
        int* __restrict__ row_ptr, unsigned int* __restrict__ count,
        const float* __restrict__ x, float* __restrict__ dinv,
        float2* __restrict__ y, float4* __restrict__ triple,
        int cap, int N) {
    __shared__ unsigned int lp[LCAP];
    __shared__ unsigned int lh[CPB];
    __shared__ int lofs[CPB];
    __shared__ unsigned int swave[4];
    int b = blockIdx.x;
    int t = threadIdx.x;
    int w = t >> 6, lane = t & 63;
    int c0 = b << BSHIFT;
    int s = b * cap;
    int cntb = bcur[b * PAD];                // padded size incl sentinels
    if (t < CPB) lh[t] = 0u;
    if (b == 0 && t == 0) {                  // zero pad slots
        y[N] = make_float2(0.0f, 0.0f);
        triple[N] = make_float4(0.0f, 0.0f, 0.0f, 0.0f);
    }
    __syncthreads();
    for (int j = t; j < cntb; j += CTHREADS) {
        unsigned int u = buf[s + j];
        lp[j] = u;
        if (u != SENT) atomicAdd(&lh[u >> 24], 1u);
    }
    __syncthreads();
    // scan over 256 cols: waves 0-3, one entry per lane
    unsigned int v = 0, pv = 0, sc = 0;
    int i0 = (w << 6) | lane;                // 0..255 for waves 0-3
    if (w < 4) {
        v = lh[i0];
        pv = (v + 7u) & ~7u;                 // pad each col segment to multiple of 8
        sc = pv;
        #pragma unroll
        for (int off = 1; off < 64; off <<= 1) {
            unsigned int u = __shfl_up(sc, off);
            if (lane >= off) sc += u;
        }
        if (lane == 63) swave[w] = sc;
    }
    __syncthreads();
    int myexcl = 0;
    if (w < 4) {
        unsigned int woff = 0;
        for (int k = 0; k < w; ++k) woff += swave[k];
        myexcl = s + (int)(woff + sc - pv);
        int c = c0 + i0;
        if (c < N) {
            row_ptr[c] = myexcl;
            count[c] = v;
            float dv = rsqrtf((float)v + 1.0f);
            dinv[c] = dv;
            float2 xv = ((const float2*)x)[c];
            y[c] = make_float2(dv * xv.x, dv * xv.y);
        }
        lofs[i0] = myexcl;
    }
    __syncthreads();
    for (int j = t; j < cntb; j += CTHREADS) {
        unsigned int u = lp[j];
        if (u != SENT) {
            int pos = atomicAdd(&lofs[u >> 24], 1);
            buf[pos] = u & 0x00FFFFFFu;
        }
    }
    __syncthreads();
    if (w < 4) {
        for (unsigned int k = v; k < pv; ++k) buf[myexcl + k] = (unsigned int)N;
    }
}

// ================= compute pipeline (all f32) =================

// fallback-only prep
__global__ void k_prep(const float* __restrict__ x, const unsigned int* __restrict__ count,
                       float* __restrict__ dinv, float2* __restrict__ y,
                       float4* __restrict__ triple, int N) {
    int i = blockIdx.x * blockDim.x + threadIdx.x;
    if (i == 0) {
        y[N] = make_float2(0.0f, 0.0f);
        triple[N] = make_float4(0.0f, 0.0f, 0.0f, 0.0f);
    }
    if (i >= N) return;
    float dv = rsqrtf((float)count[i] + 1.0f);
    dinv[i] = dv;
    float2 xv = ((const float2*)x)[i];
    y[i] = make_float2(dv * xv.x, dv * xv.y);
}

// layer-1 aggregation in input space: triple[i] = (dv*zx, dv*zy, dv); 8 lanes/node
__global__ void k_agg1(const int* __restrict__ row_ptr, const unsigned int* __restrict__ count,
                       const int* __restrict__ sorted_row, const float2* __restrict__ y,
                       const float* __restrict__ dinv, float4* __restrict__ triple, int N) {
    int t = threadIdx.x;
    int i = blockIdx.x * 32 + (t >> 3), l = t & 7;
    if (i >= N) return;
    int s = row_ptr[i];
    int e = s + (int)count[i];
    float zx = 0.0f, zy = 0.0f;
    for (int j = s + l; j < e; j += 8) {
        float2 yv = y[sorted_row[j]];
        zx += yv.x; zy += yv.y;
    }
    #pragma unroll
    for (int m = 4; m >= 1; m >>= 1) {
        zx += __shfl_xor(zx, m);
        zy += __shfl_xor(zy, m);
    }
    if (l == 0) {
        float2 yi = y[i];                  // self loop
        zx += yi.x; zy += yi.y;
        float dv = dinv[i];
        triple[i] = make_float4(dv * zx, dv * zy, dv, 0.0f);
    }
}

__device__ __forceinline__ float4 f4fma(float s, float4 m, float4 a) {
    return make_float4(fmaf(s, m.x, a.x), fmaf(s, m.y, a.y),
                       fmaf(s, m.z, a.z), fmaf(s, m.w, a.w));
}
__device__ __forceinline__ float4 f4relu(float4 q) {
    return make_float4(fmaxf(q.x, 0.f), fmaxf(q.y, 0.f), fmaxf(q.z, 0.f), fmaxf(q.w, 0.f));
}
#define EDGE_TERM(tt) acc = f4fma((tt).z, f4relu(f4fma((tt).x, w0, f4fma((tt).y, w1, bb))), acc)

// layer-2 agg + pool: 8 lanes/node (4 features/lane as float4), unroll 16 (2 chunks in flight).
__global__ void __launch_bounds__(256)
k_agg_pool(const int* __restrict__ row_ptr, const unsigned int* __restrict__ count,
           const int* __restrict__ sorted_row, const float4* __restrict__ triple,
           const float* __restrict__ W1, const float* __restrict__ b1,
           const int* __restrict__ batch, float* __restrict__ pool,
           float* __restrict__ cnt, int N) {
    __shared__ float sh[32][FDIM];
    __shared__ int sb[32];
    int t = threadIdx.x;
    int n = t >> 3, l = t & 7;
    int i = blockIdx.x * 32 + n;
    int fa = 4 * l;
    float4 w0 = *(const float4*)(W1 + fa);
    float4 w1 = *(const float4*)(W1 + FDIM + fa);
    float4 bb = *(const float4*)(b1 + fa);
    float4 acc = make_float4(0.f, 0.f, 0.f, 0.f);
    int bt = -1;
    if (i < N) {
        float4 ts = triple[i];              // self
        float dv = ts.z;
        EDGE_TERM(ts);
        int s = row_ptr[i];
        int pv = ((int)count[i] + 7) & ~7;
        int end16 = s + (pv & ~15);
        int j = s;
        for (; j < end16; j += 16) {
            int4 ra = *(const int4*)(sorted_row + j);
            int4 rb = *(const int4*)(sorted_row + j + 4);
            int4 rc = *(const int4*)(sorted_row + j + 8);
            int4 rd = *(const int4*)(sorted_row + j + 12);
            float4 t0 = triple[ra.x], t1 = triple[ra.y], t2 = triple[ra.z], t3 = triple[ra.w];
            float4 t4 = triple[rb.x], t5 = triple[rb.y], t6 = triple[rb.z], t7 = triple[rb.w];
            float4 t8 = triple[rc.x], t9 = triple[rc.y], ta = triple[rc.z], tb = triple[rc.w];
            float4 tc = triple[rd.x], td = triple[rd.y], te = triple[rd.z], tf = triple[rd.w];
            EDGE_TERM(t0); EDGE_TERM(t1); EDGE_TERM(t2); EDGE_TERM(t3);
            EDGE_TERM(t4); EDGE_TERM(t5); EDGE_TERM(t6); EDGE_TERM(t7);
            EDGE_TERM(t8); EDGE_TERM(t9); EDGE_TERM(ta); EDGE_TERM(tb);
            EDGE_TERM(tc); EDGE_TERM(td); EDGE_TERM(te); EDGE_TERM(tf);
        }
        if (pv & 8) {
            int4 ra = *(const int4*)(sorted_row + j);
            int4 rb = *(const int4*)(sorted_row + j + 4);
            float4 t0 = triple[ra.x], t1 = triple[ra.y], t2 = triple[ra.z], t3 = triple[ra.w];
            float4 t4 = triple[rb.x], t5 = triple[rb.y], t6 = triple[rb.z], t7 = triple[rb.w];
            EDGE_TERM(t0); EDGE_TERM(t1); EDGE_TERM(t2); EDGE_TERM(t3);
            EDGE_TERM(t4); EDGE_TERM(t5); EDGE_TERM(t6); EDGE_TERM(t7);
        }
        acc.x *= dv; acc.y *= dv; acc.z *= dv; acc.w *= dv;
        bt = batch[i];
    }
    *(float4*)&sh[n][fa] = acc;
    if (l == 0) sb[n] = bt;
    __syncthreads();
    if (bt >= 0 && (n == 0 || sb[n - 1] != bt)) {   // segment leader
        float4 ssum = acc;
        int m = n + 1;
        for (; m < 32 && sb[m] == bt; ++m) {
            float4 o = *(const float4*)&sh[m][fa];
            ssum.x += o.x; ssum.y += o.y; ssum.z += o.z; ssum.w += o.w;
        }
        atomicAdd(&pool[bt * FDIM + fa],     ssum.x);
        atomicAdd(&pool[bt * FDIM + fa + 1], ssum.y);
        atomicAdd(&pool[bt * FDIM + fa + 2], ssum.z);
        atomicAdd(&pool[bt * FDIM + fa + 3], ssum.w);
        if (l == 0) atomicAdd(&cnt[bt], (float)(m - n));
    }
}

// out[g] = (pool[g]/cnt[g]) @ W2 + b2   (8 graphs/WG)
__global__ void k_out(const float* __restrict__ pool, const float* __restrict__ cnt,
                      const float* __restrict__ W2, const float* __restrict__ b2,
                      float* __restrict__ out, int G) {
    __shared__ float sW[FDIM * FDIM];
    int t = threadIdx.x;
    for (int k = t; k < FDIM * FDIM; k += 256) sW[k] = W2[k];
    __syncthreads();
    int g = blockIdx.x * 8 + (t >> 5), f = t & 31;
    if (g >= G) return;
    float c = cnt[g];
    float o = 0.0f;
    if (c > 0.0f) {
        float s = 0.0f;
        #pragma unroll
        for (int k = 0; k < FDIM; ++k) s = fmaf(pool[g * FDIM + k], sW[k * FDIM + f], s);
        o = fmaf(s, 1.0f / c, b2[f]);
    }
    out[g * FDIM + f] = o;
}

// ================= compact correct-but-slow fallback (atomic path) =================

__global__ void k_fhist(const int* __restrict__ col, unsigned int* __restrict__ count, int E) {
    int i = blockIdx.x * blockDim.x + threadIdx.x;
    if (i < E) atomicAdd(&count[col[i]], 1u);
}
__global__ void k_fsc2(const int* __restrict__ row, const int* __restrict__ col,
                       const float2* __restrict__ y, float* __restrict__ z, int E) {
    int e = blockIdx.x * blockDim.x + threadIdx.x;
    if (e >= E) return;
    float2 yv = y[row[e]];
    int c = col[e];
    atomicAdd(&z[2 * c],     yv.x);
    atomicAdd(&z[2 * c + 1], yv.y);
}
__global__ void k_fmkt(const float* __restrict__ z, const float2* __restrict__ y,
                       const float* __restrict__ dinv, float4* __restrict__ triple, int N) {
    int i = blockIdx.x * blockDim.x + threadIdx.x;
    if (i >= N) return;
    float dv = dinv[i];
    float2 yi = y[i];
    triple[i] = make_float4(dv * (z[2 * i] + yi.x), dv * (z[2 * i + 1] + yi.y), dv, 0.0f);
}
__global__ void k_fsc32(const int* __restrict__ row, const int* __restrict__ col,
                        const float4* __restrict__ triple, const float* __restrict__ W1,
                        const float* __restrict__ b1, float* __restrict__ v, int total) {
    int idx = blockIdx.x * blockDim.x + threadIdx.x;
    if (idx >= total) return;
    int e = idx >> 5, f = idx & 31;
    float4 tr = triple[row[e]];
    float u = tr.z * fmaxf(fmaf(tr.x, W1[f], fmaf(tr.y, W1[FDIM + f], b1[f])), 0.0f);
    atomicAdd(&v[col[e] * FDIM + f], u);
}
__global__ void k_ffin(const float4* __restrict__ triple, const float* __restrict__ v,
                       const float* __restrict__ W1, const float* __restrict__ b1,
                       const int* __restrict__ batch, float* __restrict__ pool,
                       float* __restrict__ cnt, int N) {
    int idx = blockIdx.x * blockDim.x + threadIdx.x;
    int i = idx >> 5, f = idx & 31;
    if (i >= N) return;
    float4 tr = triple[i];
    float u = tr.z * fmaxf(fmaf(tr.x, W1[f], fmaf(tr.y, W1[FDIM + f], b1[f])), 0.0f);
    float w = tr.z * (u + v[i * FDIM + f]);
    int b = batch[i];
    atomicAdd(&pool[b * FDIM + f], w);
    if (f == 0) atomicAdd(&cnt[b], 1.0f);
}

extern "C" void kernel_launch(void* const* d_in, const int* in_sizes, int n_in,
                              void* d_out, int out_size, void* d_ws, size_t ws_size,
                              hipStream_t stream) {
    const float* x   = (const float*)d_in[0];
    const int*   ei  = (const int*)d_in[1];
    const int* batch = (const int*)d_in[2];
    const float* W1  = (const float*)d_in[4];
    const float* b1  = (const float*)d_in[5];
    const float* W2  = (const float*)d_in[6];
    const float* b2  = (const float*)d_in[7];
    float* out = (float*)d_out;

    int N = in_sizes[0] / 2;
    int E = in_sizes[1] / 2;
    int G = out_size / FDIM;

    const int* row = ei;
    const int* col = ei + E;

    int NB = (N + 255) / 256;
    int NBUK = (N + CMASK) >> BSHIFT;
    int ntiles = (E + BNT - 1) / BNT;

    // fixed bucket capacity: payload mean + per-segment pad mean (~8) + ~13-sigma slack
    int capBase = (E + NBUK - 1) / NBUK;
    int cap = capBase + ntiles * 8 + 1536;
    cap = (cap + 15) & ~15;

    // primary layout (u32 units)
    size_t off = 0;
    size_t o_bcur = off;  off += (size_t)NBUK * PAD;
    size_t o_cnt  = off;  off += N;           // count
    size_t o_rp   = off;  off += N;           // row_ptr
    size_t o_dv   = off;  off += N;           // dinv
    size_t o_y    = off;  off += 2ull * (N + 1);
    off = (off + 3) & ~(size_t)3;             // 16B align
    size_t o_tr   = off;  off += 4ull * (N + 1);
    size_t o_buf  = off;  off += (size_t)NBUK * cap;
    size_t o_pool = off;  off += 32ull * G;
    size_t o_cg   = off;  off += G;
    size_t elemsNew = off;

    unsigned int* W = (unsigned int*)d_ws;

    if (ws_size >= elemsNew * 4 && N < (1 << 24) && NBUK <= MAXBUK && cap <= LCAP) {
        int* bcur           = (int*)(W + o_bcur);
        unsigned int* count = (unsigned int*)(W + o_cnt);
        int* row_ptr        = (int*)(W + o_rp);
        float* dinv         = (float*)(W + o_dv);
        float2* y           = (float2*)(W + o_y);
        float4* triple      = (float4*)(W + o_tr);
        unsigned int* buf   = W + o_buf;      // pairs, then sorted_row in place
        float* pool         = (float*)(W + o_pool);
        float* cntg         = (float*)(W + o_cg);

        int nb = NBUK * PAD;
        int np = G * FDIM + G;
        int zgrid = (max(nb, np) + 255) / 256;
        k_zero<<<zgrid, 256, 0, stream>>>(bcur, pool, nb, np);

        k_binsort<<<ntiles, BTHREADS, 0, stream>>>(row, col, bcur, buf, E, cap, NBUK);
        k_csort<<<NBUK, CTHREADS, 0, stream>>>(buf, bcur, row_ptr, count, x, dinv, y, triple, cap, N);

        k_agg1<<<(N + 31) / 32, 256, 0, stream>>>(row_ptr, count, (const int*)buf, y, dinv,
                                                  triple, N);
        k_agg_pool<<<(N + 31) / 32, 256, 0, stream>>>(row_ptr, count, (const int*)buf, triple,
                                                      W1, b1, batch, pool, cntg, N);
        k_out<<<(G + 7) / 8, 256, 0, stream>>>(pool, cntg, W2, b2, out, G);
    } else {
        // compact fallback: atomic scatter (correct, slow; not expected to run)
        unsigned int* count = (unsigned int*)d_ws;             // N
        float* dinv         = (float*)(count + N);             // N
        float2* y           = (float2*)(dinv + N);             // N+1
        float* z            = (float*)(y + N + 1);             // 2N
        size_t toff = ((size_t)(z + 2 * N - (float*)d_ws) + 3) & ~(size_t)3;
        float4* triple      = (float4*)((float*)d_ws + toff);  // N+1
        float* v            = (float*)(triple + N + 1);        // 32N
        float* pool         = v + 32ull * N;                   // 32G
        float* cntg         = pool + 32ull * G;                // G

        hipMemsetAsync(count, 0, (size_t)N * 4, stream);
        hipMemsetAsync(z, 0, (size_t)N * 8, stream);
        hipMemsetAsync(v, 0, (size_t)N * FDIM * 4, stream);
        hipMemsetAsync(pool, 0, (size_t)(G * FDIM + G) * 4, stream);

        k_fhist<<<(E + 255) / 256, 256, 0, stream>>>(col, count, E);
        k_prep<<<NB, 256, 0, stream>>>(x, count, dinv, y, triple, N);
        k_fsc2<<<(E + 255) / 256, 256, 0, stream>>>(row, col, y, z, E);
        k_fmkt<<<NB, 256, 0, stream>>>(z, y, dinv, triple, N);
        int ts = E * FDIM;
        k_fsc32<<<(ts + 255) / 256, 256, 0, stream>>>(row, col, triple, W1, b1, v, ts);
        k_ffin<<<(N * FDIM + 255) / 256, 256, 0, stream>>>(triple, v, W1, b1, batch, pool, cntg, N);
        k_out<<<(G + 7) / 8, 256, 0, stream>>>(pool, cntg, W2, b2, out, G);
    }
}

// Round 18
// 115.809 us; speedup vs baseline: 1.3429x; 1.0359x over previous
//
#include <hip/hip_runtime.h>

#define FDIM 32
#define BSHIFT 8                 // 256 cols per bucket
#define CPB (1 << BSHIFT)
#define CMASK (CPB - 1)
#define PAD 16                   // cursor stride: 16 u32 = 64B (one cacheline)
#define MAXBUK 512
#define BTHREADS 512
#define CTHREADS 512
#define LPMAX 12544              // binsort LDS staging capacity (49 KB)
#define LCAP 13312               // csort LDS staging capacity (52 KB)
#define SENT 0xFFFFFFFFu

// ---------- one-launch zero of bcur + pool + cnt ----------
__global__ void k_zero(int* __restrict__ bcur, float* __restrict__ pool, int nb, int np) {
    int i = blockIdx.x * blockDim.x + threadIdx.x;
    if (i < nb) bcur[i] = 0;
    if (i < np) pool[i] = 0.0f;
}

// ---------- LDS-staged binning; 64B-aligned sentinel-padded segments ----------
// pack: (col & 255) << 24 | row   (needs N < 2^24). Runtime tile size bnt (<= LPMAX).
__global__ void __launch_bounds__(BTHREADS)
k_binsort(const int* __restrict__ row, const int* __restrict__ col,
          int* bcur, unsigned int* __restrict__ buf, int E, int bnt, int cap, int NBUK) {
    __shared__ unsigned int lh[MAXBUK];      // hist -> global cursor
    __shared__ int lbase[MAXBUK];            // local exclusive base (monotone)
    __shared__ int gbase[MAXBUK];            // global segment base (16-aligned)
    __shared__ unsigned int swave[4];
    __shared__ unsigned int lpair[LPMAX];    // staged packed pairs (rank order)
    int t = threadIdx.x;
    int w = t >> 6, lane = t & 63;
    int base = blockIdx.x * bnt;
    int end = min(base + bnt, E);
    int tilesz = end - base;
    int nq = tilesz >> 2;
    int rem = tilesz & 3;

    lh[t] = 0u;                              // BTHREADS==MAXBUK
    __syncthreads();

    // phase 1: tile histogram; int4-vectorized col loads
    for (int q = t; q < nq; q += BTHREADS) {
        int4 c4 = *(const int4*)(col + base + 4 * q);
        atomicAdd(&lh[c4.x >> BSHIFT], 1u);
        atomicAdd(&lh[c4.y >> BSHIFT], 1u);
        atomicAdd(&lh[c4.z >> BSHIFT], 1u);
        atomicAdd(&lh[c4.w >> BSHIFT], 1u);
    }
    if (t < rem) atomicAdd(&lh[col[base + (nq << 2) + t] >> BSHIFT], 1u);
    __syncthreads();

    // wave-shuffle exclusive scan of lh[0..512) -> lbase (waves 0-3 only)
    if (w < 4) {
        int i0 = w * 128 + lane * 2;
        unsigned int a = lh[i0], b = lh[i0 + 1];
        unsigned int sum = a + b;
        unsigned int sc = sum;
        #pragma unroll
        for (int off = 1; off < 64; off <<= 1) {
            unsigned int u = __shfl_up(sc, off);
            if (lane >= off) sc += u;
        }
        if (lane == 63) swave[w] = sc;
        __syncthreads();
        unsigned int woff = 0;
        for (int k = 0; k < w; ++k) woff += swave[k];
        lbase[i0]     = (int)(woff + sc - sum);
        lbase[i0 + 1] = (int)(woff + sc - sum + a);
    } else {
        __syncthreads();
    }
    __syncthreads();

    // phase 2: reserve 16-aligned global segments inside fixed-capacity regions
    for (int bb = t; bb < NBUK; bb += BTHREADS) {
        unsigned int c = lh[bb];
        unsigned int cp = (c + 15u) & ~15u;
        int g = bb * cap + (cp ? atomicAdd(&bcur[bb * PAD], (int)cp) : 0);
        gbase[bb] = g;
        lh[bb] = (unsigned int)g;
    }
    __syncthreads();

    // phase 3a: re-read (col,row) int4, scatter into LDS by rank
    for (int q = t; q < nq; q += BTHREADS) {
        int eb = base + 4 * q;
        int4 c4 = *(const int4*)(col + eb);
        int4 r4 = *(const int4*)(row + eb);
        int cc[4] = {c4.x, c4.y, c4.z, c4.w};
        int rr[4] = {r4.x, r4.y, r4.z, r4.w};
        #pragma unroll
        for (int k = 0; k < 4; ++k) {
            int bb = cc[k] >> BSHIFT;
            int gpos = (int)atomicAdd(&lh[bb], 1u);
            int lslot = gpos - gbase[bb] + lbase[bb];
            lpair[lslot] = ((unsigned int)(cc[k] & CMASK) << 24) | (unsigned int)rr[k];
        }
    }
    if (t < rem) {
        int e = base + (nq << 2) + t;
        int c = col[e];
        int bb = c >> BSHIFT;
        int gpos = (int)atomicAdd(&lh[bb], 1u);
        int lslot = gpos - gbase[bb] + lbase[bb];
        lpair[lslot] = ((unsigned int)(c & CMASK) << 24) | (unsigned int)row[e];
    }
    __syncthreads();

    // phase 3b: linear LDS -> coalesced, exclusively-owned global segment writes
    for (int j = t; j < tilesz; j += BTHREADS) {
        int pos = 0;
        #pragma unroll
        for (int step = 256; step; step >>= 1) {
            int np = pos + step;
            if (np < MAXBUK && lbase[np] <= j) pos = np;
        }
        buf[gbase[pos] + (j - lbase[pos])] = lpair[j];
    }

    // sentinel fill of segment pads (tail lines stay single-writer)
    for (int bb = t; bb < NBUK; bb += BTHREADS) {
        int lb = lbase[bb];
        int cend = (bb + 1 < NBUK) ? lbase[bb + 1] : tilesz;
        int c = cend - lb;
        int cp = (c + 15) & ~15;
        int g = gbase[bb];
        for (int k = c; k < cp; ++k) buf[g + k] = SENT;
    }
}

// ---------- per-bucket fine sort (in place, 8-padded), sentinel-aware, + fused prep ----------
__global__ void __launch_bounds__(CTHREADS)
k_csort(unsigned int* __restrict__ buf, const int* __restrict__ bcur,
        int* __restrict__ row_ptr, unsigned int* __restrict__ count,
        const float* __restrict__ x, float* __restrict__ dinv,
        float2* __restrict__ y, float4* __restrict__ triple,
        int cap, int N) {
    __shared__ unsigned int lp[LCAP];
    __shared__ unsigned int lh[CPB];
    __shared__ int lofs[CPB];
    __shared__ unsigned int swave[4];
    int b = blockIdx.x;
    int t = threadIdx.x;
    int w = t >> 6, lane = t & 63;
    int c0 = b << BSHIFT;
    int s = b * cap;
    int cntb = bcur[b * PAD];                // padded size incl sentinels
    if (t < CPB) lh[t] = 0u;
    if (b == 0 && t == 0) {                  // zero pad slots
        y[N] = make_float2(0.0f, 0.0f);
        triple[N] = make_float4(0.0f, 0.0f, 0.0f, 0.0f);
    }
    __syncthreads();
    for (int j = t; j < cntb; j += CTHREADS) {
        unsigned int u = buf[s + j];
        lp[j] = u;
        if (u != SENT) atomicAdd(&lh[u >> 24], 1u);
    }
    __syncthreads();
    // scan over 256 cols: waves 0-3, one entry per lane
    unsigned int v = 0, pv = 0, sc = 0;
    int i0 = (w << 6) | lane;                // 0..255 for waves 0-3
    if (w < 4) {
        v = lh[i0];
        pv = (v + 7u) & ~7u;                 // pad each col segment to multiple of 8
        sc = pv;
        #pragma unroll
        for (int off = 1; off < 64; off <<= 1) {
            unsigned int u = __shfl_up(sc, off);
            if (lane >= off) sc += u;
        }
        if (lane == 63) swave[w] = sc;
    }
    __syncthreads();
    int myexcl = 0;
    if (w < 4) {
        unsigned int woff = 0;
        for (int k = 0; k < w; ++k) woff += swave[k];
        myexcl = s + (int)(woff + sc - pv);
        int c = c0 + i0;
        if (c < N) {
            row_ptr[c] = myexcl;
            count[c] = v;
            float dv = rsqrtf((float)v + 1.0f);
            dinv[c] = dv;
            float2 xv = ((const float2*)x)[c];
            y[c] = make_float2(dv * xv.x, dv * xv.y);
        }
        lofs[i0] = myexcl;
    }
    __syncthreads();
    for (int j = t; j < cntb; j += CTHREADS) {
        unsigned int u = lp[j];
        if (u != SENT) {
            int pos = atomicAdd(&lofs[u >> 24], 1);
            buf[pos] = u & 0x00FFFFFFu;
        }
    }
    __syncthreads();
    if (w < 4) {
        for (unsigned int k = v; k < pv; ++k) buf[myexcl + k] = (unsigned int)N;
    }
}

// ================= compute pipeline (all f32) =================

// fallback-only prep
__global__ void k_prep(const float* __restrict__ x, const unsigned int* __restrict__ count,
                       float* __restrict__ dinv, float2* __restrict__ y,
                       float4* __restrict__ triple, int N) {
    int i = blockIdx.x * blockDim.x + threadIdx.x;
    if (i == 0) {
        y[N] = make_float2(0.0f, 0.0f);
        triple[N] = make_float4(0.0f, 0.0f, 0.0f, 0.0f);
    }
    if (i >= N) return;
    float dv = rsqrtf((float)count[i] + 1.0f);
    dinv[i] = dv;
    float2 xv = ((const float2*)x)[i];
    y[i] = make_float2(dv * xv.x, dv * xv.y);
}

// layer-1 aggregation in input space: triple[i] = (dv*zx, dv*zy, dv)
// 8 lanes/node; padded segments (pad idx N -> y[N]=0), unroll 16 (2 gathers in flight)
__global__ void k_agg1(const int* __restrict__ row_ptr, const unsigned int* __restrict__ count,
                       const int* __restrict__ sorted_row, const float2* __restrict__ y,
                       const float* __restrict__ dinv, float4* __restrict__ triple, int N) {
    int t = threadIdx.x;
    int i = blockIdx.x * 32 + (t >> 3), l = t & 7;
    if (i >= N) return;
    int s = row_ptr[i];
    int pv = ((int)count[i] + 7) & ~7;
    float zx = 0.0f, zy = 0.0f;
    int end16 = s + (pv & ~15);
    int j = s;
    for (; j < end16; j += 16) {
        int i0 = sorted_row[j + l];
        int i1 = sorted_row[j + 8 + l];
        float2 a = y[i0];
        float2 b = y[i1];
        zx += a.x; zy += a.y;
        zx += b.x; zy += b.y;
    }
    if (pv & 8) {
        int i0 = sorted_row[j + l];
        float2 a = y[i0];
        zx += a.x; zy += a.y;
    }
    #pragma unroll
    for (int m = 4; m >= 1; m >>= 1) {
        zx += __shfl_xor(zx, m);
        zy += __shfl_xor(zy, m);
    }
    if (l == 0) {
        float2 yi = y[i];                  // self loop
        zx += yi.x; zy += yi.y;
        float dv = dinv[i];
        triple[i] = make_float4(dv * zx, dv * zy, dv, 0.0f);
    }
}

__device__ __forceinline__ float4 f4fma(float s, float4 m, float4 a) {
    return make_float4(fmaf(s, m.x, a.x), fmaf(s, m.y, a.y),
                       fmaf(s, m.z, a.z), fmaf(s, m.w, a.w));
}
__device__ __forceinline__ float4 f4relu(float4 q) {
    return make_float4(fmaxf(q.x, 0.f), fmaxf(q.y, 0.f), fmaxf(q.z, 0.f), fmaxf(q.w, 0.f));
}
#define EDGE_TERM(tt) acc = f4fma((tt).z, f4relu(f4fma((tt).x, w0, f4fma((tt).y, w1, bb))), acc)

// layer-2 agg + pool: 8 lanes/node (4 features/lane as float4), unroll 16.
__global__ void __launch_bounds__(256)
k_agg_pool(const int* __restrict__ row_ptr, const unsigned int* __restrict__ count,
           const int* __restrict__ sorted_row, const float4* __restrict__ triple,
           const float* __restrict__ W1, const float* __restrict__ b1,
           const int* __restrict__ batch, float* __restrict__ pool,
           float* __restrict__ cnt, int N) {
    __shared__ float sh[32][FDIM];
    __shared__ int sb[32];
    int t = threadIdx.x;
    int n = t >> 3, l = t & 7;
    int i = blockIdx.x * 32 + n;
    int fa = 4 * l;
    float4 w0 = *(const float4*)(W1 + fa);
    float4 w1 = *(const float4*)(W1 + FDIM + fa);
    float4 bb = *(const float4*)(b1 + fa);
    float4 acc = make_float4(0.f, 0.f, 0.f, 0.f);
    int bt = -1;
    if (i < N) {
        float4 ts = triple[i];              // self
        float dv = ts.z;
        EDGE_TERM(ts);
        int s = row_ptr[i];
        int pv = ((int)count[i] + 7) & ~7;
        int end16 = s + (pv & ~15);
        int j = s;
        for (; j < end16; j += 16) {
            int4 ra = *(const int4*)(sorted_row + j);
            int4 rb = *(const int4*)(sorted_row + j + 4);
            int4 rc = *(const int4*)(sorted_row + j + 8);
            int4 rd = *(const int4*)(sorted_row + j + 12);
            float4 t0 = triple[ra.x], t1 = triple[ra.y], t2 = triple[ra.z], t3 = triple[ra.w];
            float4 t4 = triple[rb.x], t5 = triple[rb.y], t6 = triple[rb.z], t7 = triple[rb.w];
            float4 t8 = triple[rc.x], t9 = triple[rc.y], ta = triple[rc.z], tb = triple[rc.w];
            float4 tc = triple[rd.x], td = triple[rd.y], te = triple[rd.z], tf = triple[rd.w];
            EDGE_TERM(t0); EDGE_TERM(t1); EDGE_TERM(t2); EDGE_TERM(t3);
            EDGE_TERM(t4); EDGE_TERM(t5); EDGE_TERM(t6); EDGE_TERM(t7);
            EDGE_TERM(t8); EDGE_TERM(t9); EDGE_TERM(ta); EDGE_TERM(tb);
            EDGE_TERM(tc); EDGE_TERM(td); EDGE_TERM(te); EDGE_TERM(tf);
        }
        if (pv & 8) {
            int4 ra = *(const int4*)(sorted_row + j);
            int4 rb = *(const int4*)(sorted_row + j + 4);
            float4 t0 = triple[ra.x], t1 = triple[ra.y], t2 = triple[ra.z], t3 = triple[ra.w];
            float4 t4 = triple[rb.x], t5 = triple[rb.y], t6 = triple[rb.z], t7 = triple[rb.w];
            EDGE_TERM(t0); EDGE_TERM(t1); EDGE_TERM(t2); EDGE_TERM(t3);
            EDGE_TERM(t4); EDGE_TERM(t5); EDGE_TERM(t6); EDGE_TERM(t7);
        }
        acc.x *= dv; acc.y *= dv; acc.z *= dv; acc.w *= dv;
        bt = batch[i];
    }
    *(float4*)&sh[n][fa] = acc;
    if (l == 0) sb[n] = bt;
    __syncthreads();
    if (bt >= 0 && (n == 0 || sb[n - 1] != bt)) {   // segment leader
        float4 ssum = acc;
        int m = n + 1;
        for (; m < 32 && sb[m] == bt; ++m) {
            float4 o = *(const float4*)&sh[m][fa];
            ssum.x += o.x; ssum.y += o.y; ssum.z += o.z; ssum.w += o.w;
        }
        atomicAdd(&pool[bt * FDIM + fa],     ssum.x);
        atomicAdd(&pool[bt * FDIM + fa + 1], ssum.y);
        atomicAdd(&pool[bt * FDIM + fa + 2], ssum.z);
        atomicAdd(&pool[bt * FDIM + fa + 3], ssum.w);
        if (l == 0) atomicAdd(&cnt[bt], (float)(m - n));
    }
}

// out[g] = (pool[g]/cnt[g]) @ W2 + b2   (8 graphs/WG)
__global__ void k_out(const float* __restrict__ pool, const float* __restrict__ cnt,
                      const float* __restrict__ W2, const float* __restrict__ b2,
                      float* __restrict__ out, int G) {
    __shared__ float sW[FDIM * FDIM];
    int t = threadIdx.x;
    for (int k = t; k < FDIM * FDIM; k += 256) sW[k] = W2[k];
    __syncthreads();
    int g = blockIdx.x * 8 + (t >> 5), f = t & 31;
    if (g >= G) return;
    float c = cnt[g];
    float o = 0.0f;
    if (c > 0.0f) {
        float s = 0.0f;
        #pragma unroll
        for (int k = 0; k < FDIM; ++k) s = fmaf(pool[g * FDIM + k], sW[k * FDIM + f], s);
        o = fmaf(s, 1.0f / c, b2[f]);
    }
    out[g * FDIM + f] = o;
}

// ================= compact correct-but-slow fallback (atomic path) =================

__global__ void k_fhist(const int* __restrict__ col, unsigned int* __restrict__ count, int E) {
    int i = blockIdx.x * blockDim.x + threadIdx.x;
    if (i < E) atomicAdd(&count[col[i]], 1u);
}
__global__ void k_fsc2(const int* __restrict__ row, const int* __restrict__ col,
                       const float2* __restrict__ y, float* __restrict__ z, int E) {
    int e = blockIdx.x * blockDim.x + threadIdx.x;
    if (e >= E) return;
    float2 yv = y[row[e]];
    int c = col[e];
    atomicAdd(&z[2 * c],     yv.x);
    atomicAdd(&z[2 * c + 1], yv.y);
}
__global__ void k_fmkt(const float* __restrict__ z, const float2* __restrict__ y,
                       const float* __restrict__ dinv, float4* __restrict__ triple, int N) {
    int i = blockIdx.x * blockDim.x + threadIdx.x;
    if (i >= N) return;
    float dv = dinv[i];
    float2 yi = y[i];
    triple[i] = make_float4(dv * (z[2 * i] + yi.x), dv * (z[2 * i + 1] + yi.y), dv, 0.0f);
}
__global__ void k_fsc32(const int* __restrict__ row, const int* __restrict__ col,
                        const float4* __restrict__ triple, const float* __restrict__ W1,
                        const float* __restrict__ b1, float* __restrict__ v, int total) {
    int idx = blockIdx.x * blockDim.x + threadIdx.x;
    if (idx >= total) return;
    int e = idx >> 5, f = idx & 31;
    float4 tr = triple[row[e]];
    float u = tr.z * fmaxf(fmaf(tr.x, W1[f], fmaf(tr.y, W1[FDIM + f], b1[f])), 0.0f);
    atomicAdd(&v[col[e] * FDIM + f], u);
}
__global__ void k_ffin(const float4* __restrict__ triple, const float* __restrict__ v,
                       const float* __restrict__ W1, const float* __restrict__ b1,
                       const int* __restrict__ batch, float* __restrict__ pool,
                       float* __restrict__ cnt, int N) {
    int idx = blockIdx.x * blockDim.x + threadIdx.x;
    int i = idx >> 5, f = idx & 31;
    if (i >= N) return;
    float4 tr = triple[i];
    float u = tr.z * fmaxf(fmaf(tr.x, W1[f], fmaf(tr.y, W1[FDIM + f], b1[f])), 0.0f);
    float w = tr.z * (u + v[i * FDIM + f]);
    int b = batch[i];
    atomicAdd(&pool[b * FDIM + f], w);
    if (f == 0) atomicAdd(&cnt[b], 1.0f);
}

extern "C" void kernel_launch(void* const* d_in, const int* in_sizes, int n_in,
                              void* d_out, int out_size, void* d_ws, size_t ws_size,
                              hipStream_t stream) {
    const float* x   = (const float*)d_in[0];
    const int*   ei  = (const int*)d_in[1];
    const int* batch = (const int*)d_in[2];
    const float* W1  = (const float*)d_in[4];
    const float* b1  = (const float*)d_in[5];
    const float* W2  = (const float*)d_in[6];
    const float* b2  = (const float*)d_in[7];
    float* out = (float*)d_out;

    int N = in_sizes[0] / 2;
    int E = in_sizes[1] / 2;
    int G = out_size / FDIM;

    const int* row = ei;
    const int* col = ei + E;

    int NB = (N + 255) / 256;
    int NBUK = (N + CMASK) >> BSHIFT;

    // binsort tile size: exactly ~256 tiles, one per CU
    int bnt = (E + 255) / 256;
    bnt = (bnt + 15) & ~15;
    int ntiles = (E + bnt - 1) / bnt;

    // fixed bucket capacity: payload mean + per-segment pad mean (~8/tile) + ~13-sigma slack
    int capBase = (E + NBUK - 1) / NBUK;
    int cap = capBase + ntiles * 8 + 1536;
    cap = (cap + 15) & ~15;

    // primary layout (u32 units)
    size_t off = 0;
    size_t o_bcur = off;  off += (size_t)NBUK * PAD;
    size_t o_cnt  = off;  off += N;           // count
    size_t o_rp   = off;  off += N;           // row_ptr
    size_t o_dv   = off;  off += N;           // dinv
    size_t o_y    = off;  off += 2ull * (N + 1);
    off = (off + 3) & ~(size_t)3;             // 16B align
    size_t o_tr   = off;  off += 4ull * (N + 1);
    size_t o_buf  = off;  off += (size_t)NBUK * cap;
    size_t o_pool = off;  off += 32ull * G;
    size_t o_cg   = off;  off += G;
    size_t elemsNew = off;

    unsigned int* W = (unsigned int*)d_ws;

    if (ws_size >= elemsNew * 4 && N < (1 << 24) && NBUK <= MAXBUK &&
        cap <= LCAP && bnt <= LPMAX && (E & 3) == 0) {
        int* bcur           = (int*)(W + o_bcur);
        unsigned int* count = (unsigned int*)(W + o_cnt);
        int* row_ptr        = (int*)(W + o_rp);
        float* dinv         = (float*)(W + o_dv);
        float2* y           = (float2*)(W + o_y);
        float4* triple      = (float4*)(W + o_tr);
        unsigned int* buf   = W + o_buf;      // pairs, then sorted_row in place
        float* pool         = (float*)(W + o_pool);
        float* cntg         = (float*)(W + o_cg);

        int nb = NBUK * PAD;
        int np = G * FDIM + G;
        int zgrid = (max(nb, np) + 255) / 256;
        k_zero<<<zgrid, 256, 0, stream>>>(bcur, pool, nb, np);

        k_binsort<<<ntiles, BTHREADS, 0, stream>>>(row, col, bcur, buf, E, bnt, cap, NBUK);
        k_csort<<<NBUK, CTHREADS, 0, stream>>>(buf, bcur, row_ptr, count, x, dinv, y, triple, cap, N);

        k_agg1<<<(N + 31) / 32, 256, 0, stream>>>(row_ptr, count, (const int*)buf, y, dinv,
                                                  triple, N);
        k_agg_pool<<<(N + 31) / 32, 256, 0, stream>>>(row_ptr, count, (const int*)buf, triple,
                                                      W1, b1, batch, pool, cntg, N);
        k_out<<<(G + 7) / 8, 256, 0, stream>>>(pool, cntg, W2, b2, out, G);
    } else {
        // compact fallback: atomic scatter (correct, slow; not expected to run)
        unsigned int* count = (unsigned int*)d_ws;             // N
        float* dinv         = (float*)(count + N);             // N
        float2* y           = (float2*)(dinv + N);             // N+1
        float* z            = (float*)(y + N + 1);             // 2N
        size_t toff = ((size_t)(z + 2 * N - (float*)d_ws) + 3) & ~(size_t)3;
        float4* triple      = (float4*)((float*)d_ws + toff);  // N+1
        float* v            = (float*)(triple + N + 1);        // 32N
        float* pool         = v + 32ull * N;                   // 32G
        float* cntg         = pool + 32ull * G;                // G

        hipMemsetAsync(count, 0, (size_t)N * 4, stream);
        hipMemsetAsync(z, 0, (size_t)N * 8, stream);
        hipMemsetAsync(v, 0, (size_t)N * FDIM * 4, stream);
        hipMemsetAsync(pool, 0, (size_t)(G * FDIM + G) * 4, stream);

        k_fhist<<<(E + 255) / 256, 256, 0, stream>>>(col, count, E);
        k_prep<<<NB, 256, 0, stream>>>(x, count, dinv, y, triple, N);
        k_fsc2<<<(E + 255) / 256, 256, 0, stream>>>(row, col, y, z, E);
        k_fmkt<<<NB, 256, 0, stream>>>(z, y, dinv, triple, N);
        int ts = E * FDIM;
        k_fsc32<<<(ts + 255) / 256, 256, 0, stream>>>(row, col, triple, W1, b1, v, ts);
        k_ffin<<<(N * FDIM + 255) / 256, 256, 0, stream>>>(triple, v, W1, b1, batch, pool, cntg, N);
        k_out<<<(G + 7) / 8, 256, 0, stream>>>(pool, cntg, W2, b2, out, G);
    }
}